// Round 5
// baseline (344.349 us; speedup 1.0000x reference)
//
#include <hip/hip_runtime.h>

#define BB    4
#define TE    1024
#define TD    512
#define HH    128
#define DTILE 4
#define TTILE 64
#define ESTR  (TE + 8)              // e_s row stride: breaks d-bank aliasing
#define LOG2E 1.4426950408889634f

typedef float f32x2 __attribute__((ext_vector_type(2)));

__device__ __forceinline__ f32x2 pk_fma(f32x2 a, f32x2 b, f32x2 c) {
    return __builtin_elementwise_fma(a, b, c);
}

// Accurate-enough tanh for the proj epilogue (786K elems, off the hot path).
__device__ __forceinline__ float tanh_eval(float x) {
    float e = __builtin_amdgcn_exp2f(2.0f * LOG2E * x);
    return 1.0f - 2.0f * __builtin_amdgcn_rcpf(e + 1.0f);
}

// ---------------------------------------------------------------------------
// Kernel 1: skinny projections (M=6144, N=128, K=128) with tanh epilogue.
//
// R15: R14's LDS-staged W serialized on the LDS pipe (16 waves/CU x 160
// ds_read_b128 x 12cyc ~= 12.8us/CU). W is 64KB and L2-resident; the R13
// failure was LOCKSTEP same-line streaming (single-slice hotspot), not L2
// capacity. Fix: stream W from global but rotate the k-start per block
// (k0 = (bid&31)*4) so contemporaneous blocks hit different lines ->
// requests spread across L2 slices. No LDS, no barrier; 12 waves/CU hide
// L2-hit latency. Expected ~6-9us.
// ---------------------------------------------------------------------------
__global__ __launch_bounds__(512) void proj_gemm(
    const float* __restrict__ enc, const float* __restrict__ dec,
    const float* __restrict__ Wa,  const float* __restrict__ Ua,
    float* __restrict__ out)
{
    const int tid = threadIdx.x;
    const int bid = blockIdx.x;
    const int r0  = bid * 16;

    const float* X; const float* W; int rX0;
    if (r0 < BB * TE) { X = enc; W = Wa; rX0 = r0; }
    else              { X = dec; W = Ua; rX0 = r0 - BB * TE; }

    const int rr = tid >> 5;        // 0..15 : output row within tile
    const int c4 = tid & 31;        // 0..31 : output float4 column group

    const float* xrow = X + (size_t)(rX0 + rr) * HH;
    const float* Wc   = W + c4 * 4;

    // Split accumulators (even/odd k) to break the pk_fma dependency chain.
    f32x2 aL0 = {0.f, 0.f}, aH0 = {0.f, 0.f};
    f32x2 aL1 = {0.f, 0.f}, aH1 = {0.f, 0.f};

    auto body = [&](int k) {
        float4 w0 = *(const float4*)&Wc[(k + 0) * HH];
        float4 w1 = *(const float4*)&Wc[(k + 1) * HH];
        float4 w2 = *(const float4*)&Wc[(k + 2) * HH];
        float4 w3 = *(const float4*)&Wc[(k + 3) * HH];
        float4 xv = *(const float4*)&xrow[k];   // broadcast (same line per rr)

        aL0 = pk_fma((f32x2){xv.x, xv.x}, (f32x2){w0.x, w0.y}, aL0);
        aH0 = pk_fma((f32x2){xv.x, xv.x}, (f32x2){w0.z, w0.w}, aH0);
        aL1 = pk_fma((f32x2){xv.y, xv.y}, (f32x2){w1.x, w1.y}, aL1);
        aH1 = pk_fma((f32x2){xv.y, xv.y}, (f32x2){w1.z, w1.w}, aH1);
        aL0 = pk_fma((f32x2){xv.z, xv.z}, (f32x2){w2.x, w2.y}, aL0);
        aH0 = pk_fma((f32x2){xv.z, xv.z}, (f32x2){w2.z, w2.w}, aH0);
        aL1 = pk_fma((f32x2){xv.w, xv.w}, (f32x2){w3.x, w3.y}, aL1);
        aH1 = pk_fma((f32x2){xv.w, xv.w}, (f32x2){w3.z, w3.w}, aH1);
    };

    // Per-block k-rotation: decorrelates W line requests across blocks.
    const int k0 = (bid & 31) * 4;
    #pragma unroll 4
    for (int k = k0; k < HH; k += 4) body(k);
    #pragma unroll 4
    for (int k = 0; k < k0; k += 4) body(k);

    f32x2 aL = aL0 + aL1;
    f32x2 aH = aH0 + aH1;

    float4 o;
    o.x = tanh_eval(aL.x); o.y = tanh_eval(aL.y);
    o.z = tanh_eval(aH.x); o.w = tanh_eval(aH.y);
    *(float4*)&out[(size_t)(r0 + rr) * HH + c4 * 4] = o;
}

// ---------------------------------------------------------------------------
// Kernel 2: fused energies -> softmax -> context.
//
// R15: latency-bound at 2 blocks/CU (VALUBusy 51%, occupancy 33%, HBM 5.8%,
// bank-conflicts 0). Double TLP at constant traffic: 1024 thr/block (16
// waves), same 512-block grid -> 32 waves/CU. Phase 1: wave pairs split the
// i-range (ih = w>>3). Phase 2: 4 waves per d write quarters. Phase 3: each
// wave owns 4 enc rows per 64-tile. LDS 48.2KB -> still 2 blocks/CU.
// Per-thread math/association unchanged.
// ---------------------------------------------------------------------------
__global__ __launch_bounds__(1024, 8) void attn_fused(
    const float* __restrict__ enc,    // [B, TE, H] raw
    const float* __restrict__ ta,     // [B*TE, H]  = tanh(W_s)
    const float* __restrict__ tb,     // [B*TD, H]  = tanh(U_h)
    const float* __restrict__ Va,     // [H]
    float* __restrict__ c_out,        // [B, TD, H]
    float* __restrict__ e_out)        // [B, TD, TE]
{
    __shared__ float e_s[DTILE * ESTR];      // 16.1 KB
    __shared__ float c_red[16 * DTILE * HH]; // 32 KB

    const int tid = threadIdx.x;
    const int l   = tid & 63;
    const int w   = tid >> 6;            // 0..15
    const int b   = blockIdx.x >> 7;
    const int d0  = (blockIdx.x & 127) * DTILE;

    // ---------------- Phase 1: energies ----------------
    {
        const int w2 = w & 7;            // row-octet owner
        const int ih = w >> 3;           // i-range half (0/1)
        const int g  = l >> 3;           // group 0..7
        const int hl = l & 7;            // h-chunk offset within group
        const int dl = g & 3;            // this group's decoder step
        const int rh = g >> 2;           // row parity

        // Lane constants as f32x2: B, Bp = v*B, v (24 f32x2 = 48 regs).
        f32x2 Bl[4], Bh[4], Pl[4], Ph[4], Vl[4], Vh[4];
        #pragma unroll
        for (int j = 0; j < 4; ++j) {
            float4 vv = *(const float4*)&Va[(j * 8 + hl) * 4];
            float4 bb = *(const float4*)&tb[((size_t)b * TD + d0 + dl) * HH + (j * 8 + hl) * 4];
            Vl[j] = (f32x2){vv.x, vv.y};  Vh[j] = (f32x2){vv.z, vv.w};
            Bl[j] = (f32x2){bb.x, bb.y};  Bh[j] = (f32x2){bb.z, bb.w};
            Pl[j] = Vl[j] * Bl[j];        Ph[j] = Vh[j] * Bh[j];
        }

        const float* ta_b = ta + (size_t)b * TE * HH;

        // Wave-octet w2 covers rows {(i>>2)*64 + w2*8 + (i&3)*2 + rh}.
        auto rowOf = [&](int i) {
            return ((i >> 2) << 6) + w2 * 8 + ((i & 3) << 1) + rh;
        };

        float4 A0[4], A1[4];
        auto loadA = [&](int i, float4 (&A)[4]) {
            const float* base = ta_b + (size_t)rowOf(i) * HH;
            #pragma unroll
            for (int j = 0; j < 4; ++j)
                A[j] = *(const float4*)&base[(j * 8 + hl) * 4];
        };

        auto p1c = [&](int i, float4 (&A)[4]) {
            const f32x2 one2 = {1.0f, 1.0f};
            f32x2 n2[8], d2[8];
            #pragma unroll
            for (int j = 0; j < 4; ++j) {
                f32x2 Al = (f32x2){A[j].x, A[j].y};
                f32x2 Ah = (f32x2){A[j].z, A[j].w};
                n2[2 * j]     = pk_fma(Vl[j], Al, Pl[j]);
                n2[2 * j + 1] = pk_fma(Vh[j], Ah, Ph[j]);
                d2[2 * j]     = pk_fma(Al, Bl[j], one2);
                d2[2 * j + 1] = pk_fma(Ah, Bh[j], one2);
            }
            // Vertical packed fraction-combine tree: 8 -> 4 -> 2 -> 1.
            #pragma unroll
            for (int s = 4; s >= 1; s >>= 1) {
                #pragma unroll
                for (int k = 0; k < s; ++k) {
                    n2[k] = pk_fma(n2[2 * k], d2[2 * k + 1], n2[2 * k + 1] * d2[2 * k]);
                    d2[k] = d2[2 * k] * d2[2 * k + 1];
                }
            }
            // Horizontal: combine the two sub-fractions in .x/.y.
            float num = n2[0].x * d2[0].y + n2[0].y * d2[0].x;
            float den = d2[0].x * d2[0].y;
            float e = num * __builtin_amdgcn_rcpf(den);
            e += __shfl_xor(e, 1);
            e += __shfl_xor(e, 2);
            e += __shfl_xor(e, 4);
            if (hl == 0) e_s[dl * ESTR + rowOf(i)] = e;
        };

        const int i0 = ih * 32;
        loadA(i0, A0);
        #pragma unroll 1
        for (int i = i0; i < i0 + 30; i += 2) {
            loadA(i + 1, A1);
            p1c(i, A0);
            loadA(i + 2, A0);
            p1c(i + 1, A1);
        }
        loadA(i0 + 31, A1);
        p1c(i0 + 30, A0);
        p1c(i0 + 31, A1);
    }
    __syncthreads();   // all waves' raw energies visible

    // ------------- Phase 2: softmax (d = w&3, four waves split quarters) ----
    {
        const int d2 = w & 3, q = w >> 2;    // q = 0..3
        float ev[16];
        float m = -3.0e38f;
        #pragma unroll
        for (int i = 0; i < 16; ++i) {
            ev[i] = e_s[d2 * ESTR + i * 64 + l];
            m = fmaxf(m, ev[i]);
        }
        #pragma unroll
        for (int off = 32; off; off >>= 1) m = fmaxf(m, __shfl_xor(m, off));
        float s = 0.f;
        #pragma unroll
        for (int i = 0; i < 16; ++i) {
            ev[i] = __builtin_amdgcn_exp2f((ev[i] - m) * LOG2E);
            s += ev[i];
        }
        #pragma unroll
        for (int off = 32; off; off >>= 1) s += __shfl_xor(s, off);
        float inv = __builtin_amdgcn_rcpf(s);

        __syncthreads();   // all raw-energy reads done before overwrite
        float* eo = e_out + ((size_t)b * TD + d0 + d2) * TE;
        #pragma unroll
        for (int i = 0; i < 4; ++i) {
            int ii = q * 4 + i;
            float p = ev[ii] * inv;
            e_s[d2 * ESTR + ii * 64 + l] = p;
            eo[ii * 64 + l] = p;
        }
        __syncthreads();   // normalized p visible to all waves
    }

    // ---------------- Phase 3: context (each wave owns 4 rows per tile) -----
    const int h4 = l & 31, tsub = l >> 5;
    f32x2 accL[DTILE], accH[DTILE];
    #pragma unroll
    for (int d = 0; d < DTILE; ++d) {
        accL[d] = (f32x2){0.f, 0.f};
        accH[d] = (f32x2){0.f, 0.f};
    }

    {
        const float* enc_w = enc + ((size_t)b * TE + w * 4) * HH;
        float4 X0[2], X1[2];

        auto loadX = [&](int tt, float4 (&Xr)[2]) {
            const float* base = enc_w + (size_t)tt * TTILE * HH;
            #pragma unroll
            for (int k = 0; k < 2; ++k)
                Xr[k] = *(const float4*)&base[(tsub * 2 + k) * HH + h4 * 4];
        };

        auto p3c = [&](int tt, float4 (&Xr)[2]) {
            f32x2 ep[DTILE];
            #pragma unroll
            for (int d = 0; d < DTILE; ++d)
                ep[d] = *(const f32x2*)&e_s[d * ESTR + tt * TTILE + w * 4 + tsub * 2];
            #pragma unroll
            for (int k = 0; k < 2; ++k) {
                f32x2 xL = (f32x2){Xr[k].x, Xr[k].y};
                f32x2 xH = (f32x2){Xr[k].z, Xr[k].w};
                #pragma unroll
                for (int d = 0; d < DTILE; ++d) {
                    float p = (k == 0) ? ep[d].x : ep[d].y;
                    f32x2 pv = (f32x2){p, p};
                    accL[d] = pk_fma(pv, xL, accL[d]);
                    accH[d] = pk_fma(pv, xH, accH[d]);
                }
            }
        };

        loadX(0, X0);
        #pragma unroll 1
        for (int tt = 0; tt < 14; tt += 2) {
            loadX(tt + 1, X1);
            p3c(tt, X0);
            loadX(tt + 2, X0);
            p3c(tt + 1, X1);
        }
        loadX(15, X1);
        p3c(14, X0);
        p3c(15, X1);
    }

    // Combine tsub halves; park per-wave partials; tree-reduce across waves.
    float4 acc4[DTILE];
    #pragma unroll
    for (int d = 0; d < DTILE; ++d)
        acc4[d] = make_float4(accL[d].x, accL[d].y, accH[d].x, accH[d].y);
    #pragma unroll
    for (int d = 0; d < DTILE; ++d) {
        acc4[d].x += __shfl_xor(acc4[d].x, 32);
        acc4[d].y += __shfl_xor(acc4[d].y, 32);
        acc4[d].z += __shfl_xor(acc4[d].z, 32);
        acc4[d].w += __shfl_xor(acc4[d].w, 32);
    }
    if (tsub == 0) {
        #pragma unroll
        for (int d = 0; d < DTILE; ++d)
            *(float4*)&c_red[(w * DTILE + d) * HH + h4 * 4] = acc4[d];
    }
    __syncthreads();

    if (w < DTILE && l < 32) {
        float4 o = make_float4(0.f, 0.f, 0.f, 0.f);
        #pragma unroll
        for (int ww = 0; ww < 16; ++ww) {
            float4 p = *(const float4*)&c_red[(ww * DTILE + w) * HH + l * 4];
            o.x += p.x; o.y += p.y; o.z += p.z; o.w += p.w;
        }
        *(float4*)&c_out[((size_t)b * TD + d0 + w) * HH + l * 4] = o;
    }
}

// ---------------------------------------------------------------------------
extern "C" void kernel_launch(void* const* d_in, const int* in_sizes, int n_in,
                              void* d_out, int out_size, void* d_ws, size_t ws_size,
                              hipStream_t stream) {
    (void)in_sizes; (void)n_in; (void)out_size; (void)ws_size;

    const float* enc = (const float*)d_in[0];
    const float* dec = (const float*)d_in[1];
    const float* Wa  = (const float*)d_in[2];
    const float* Ua  = (const float*)d_in[3];
    const float* Va  = (const float*)d_in[4];

    float* c_out = (float*)d_out;
    float* e_out = (float*)d_out + BB * TD * HH;

    float* proj = (float*)d_ws;
    float* ta_p = proj;                  // tanh(W_s): [B*TE, H]
    float* tb_p = proj + BB * TE * HH;   // tanh(U_h): [B*TD, H]

    proj_gemm<<<384, 512, 0, stream>>>(enc, dec, Wa, Ua, proj);
    attn_fused<<<(BB * TD) / DTILE, 1024, 0, stream>>>(enc, ta_p, tb_p, Va, c_out, e_out);
}

// Round 6
// 127.533 us; speedup vs baseline: 2.7001x; 2.7001x over previous
//
#include <hip/hip_runtime.h>

#define BB    4
#define TE    1024
#define TD    512
#define HH    128
#define DTILE 2
#define TTILE 64
#define ESTR  (TE + 8)              // e_s row stride: breaks d-bank aliasing
#define LOG2E 1.4426950408889634f

typedef float f32x2 __attribute__((ext_vector_type(2)));

__device__ __forceinline__ f32x2 pk_fma(f32x2 a, f32x2 b, f32x2 c) {
    return __builtin_elementwise_fma(a, b, c);
}

// Accurate-enough tanh for the proj epilogue (786K elems, off the hot path).
__device__ __forceinline__ float tanh_eval(float x) {
    float e = __builtin_amdgcn_exp2f(2.0f * LOG2E * x);
    return 1.0f - 2.0f * __builtin_amdgcn_rcpf(e + 1.0f);
}

// ---------------------------------------------------------------------------
// Kernel 1: skinny projections (M=6144, N=128, K=128) with tanh epilogue.
// R14 LDS-staged-W version, EXACTLY as in the 120.76us round-4 bench.
// ---------------------------------------------------------------------------
__global__ __launch_bounds__(512, 2) void proj_gemm(
    const float* __restrict__ enc, const float* __restrict__ dec,
    const float* __restrict__ Wa,  const float* __restrict__ Ua,
    float* __restrict__ out)
{
    __shared__ float Ws[HH * HH];   // 64 KB: W[k][c], row-major
    __shared__ float Xs[16 * HH];   // 8 KB

    const int tid = threadIdx.x;
    const int r0  = blockIdx.x * 16;

    const float* X; const float* W; int rX0;
    if (r0 < BB * TE) { X = enc; W = Wa; rX0 = r0; }
    else              { X = dec; W = Ua; rX0 = r0 - BB * TE; }

    #pragma unroll
    for (int i = 0; i < 8; ++i)
        *(float4*)&Ws[i * 2048 + tid * 4] =
            *(const float4*)&W[i * 2048 + tid * 4];

    {
        const int r = tid >> 5, c = tid & 31;
        *(float4*)&Xs[r * HH + c * 4] =
            *(const float4*)&X[(size_t)(rX0 + r) * HH + c * 4];
    }
    __syncthreads();

    const int rr = tid >> 5;        // 0..15 : output row within tile
    const int c4 = tid & 31;        // 0..31 : output float4 column group

    f32x2 aL0 = {0.f, 0.f}, aH0 = {0.f, 0.f};
    f32x2 aL1 = {0.f, 0.f}, aH1 = {0.f, 0.f};

    const float* wc   = &Ws[c4 * 4];
    const float* xrow = &Xs[rr * HH];

    #pragma unroll 4
    for (int k = 0; k < HH; k += 4) {
        float4 w0 = *(const float4*)&wc[(k + 0) * HH];
        float4 w1 = *(const float4*)&wc[(k + 1) * HH];
        float4 w2 = *(const float4*)&wc[(k + 2) * HH];
        float4 w3 = *(const float4*)&wc[(k + 3) * HH];
        float4 xv = *(const float4*)&xrow[k];

        aL0 = pk_fma((f32x2){xv.x, xv.x}, (f32x2){w0.x, w0.y}, aL0);
        aH0 = pk_fma((f32x2){xv.x, xv.x}, (f32x2){w0.z, w0.w}, aH0);
        aL1 = pk_fma((f32x2){xv.y, xv.y}, (f32x2){w1.x, w1.y}, aL1);
        aH1 = pk_fma((f32x2){xv.y, xv.y}, (f32x2){w1.z, w1.w}, aH1);
        aL0 = pk_fma((f32x2){xv.z, xv.z}, (f32x2){w2.x, w2.y}, aL0);
        aH0 = pk_fma((f32x2){xv.z, xv.z}, (f32x2){w2.z, w2.w}, aH0);
        aL1 = pk_fma((f32x2){xv.w, xv.w}, (f32x2){w3.x, w3.y}, aL1);
        aH1 = pk_fma((f32x2){xv.w, xv.w}, (f32x2){w3.z, w3.w}, aH1);
    }

    f32x2 aL = aL0 + aL1;
    f32x2 aH = aH0 + aH1;

    float4 o;
    o.x = tanh_eval(aL.x); o.y = tanh_eval(aL.y);
    o.z = tanh_eval(aH.x); o.w = tanh_eval(aH.y);
    *(float4*)&out[(size_t)(r0 + rr) * HH + c4 * 4] = o;
}

// ---------------------------------------------------------------------------
// Kernel 2: fused energies -> softmax -> context.
//
// R16: revert to the PROVEN round-4 structure (57.4us; R15's restructure
// blew FETCH 17->757MB by breaking the sweep choreography). Single change:
// DTILE 4 -> 2. Grid 512 -> 1024 blocks -> 4 blocks/CU (32 waves/CU),
// attacking the grid-cap latency bound (VALUBusy 51%, occ 33%). Each wave
// keeps the IDENTICAL ascending row-octet sweep in phases 1/3; only the
// lane-group -> (d, row-offset) mapping changes (dl=g&1, 4 offsets) and
// per-block i-count halves. LDS ~16.4KB.
// ---------------------------------------------------------------------------
__global__ __launch_bounds__(512, 4) void attn_fused(
    const float* __restrict__ enc,    // [B, TE, H] raw
    const float* __restrict__ ta,     // [B*TE, H]  = tanh(W_s)
    const float* __restrict__ tb,     // [B*TD, H]  = tanh(U_h)
    const float* __restrict__ Va,     // [H]
    float* __restrict__ c_out,        // [B, TD, H]
    float* __restrict__ e_out)        // [B, TD, TE]
{
    __shared__ float e_s[DTILE * ESTR];     // 8.3 KB
    __shared__ float c_red[8 * DTILE * HH]; // 8 KB

    const int tid = threadIdx.x;
    const int l   = tid & 63;
    const int w   = tid >> 6;            // 0..7 (row-octet owner)
    const int b   = blockIdx.x >> 8;                 // 256 blocks per batch
    const int d0  = (blockIdx.x & 255) * DTILE;

    // ---------------- Phase 1: energies ----------------
    {
        const int g  = l >> 3;           // group 0..7
        const int hl = l & 7;            // h-chunk offset within group
        const int dl = g & 1;            // this group's decoder step (0/1)
        const int rp = g >> 1;           // row offset within half-octet (0..3)

        // Lane constants as f32x2: B, Bp = v*B, v.
        f32x2 Bl[4], Bh[4], Pl[4], Ph[4], Vl[4], Vh[4];
        #pragma unroll
        for (int j = 0; j < 4; ++j) {
            float4 vv = *(const float4*)&Va[(j * 8 + hl) * 4];
            float4 bb = *(const float4*)&tb[((size_t)b * TD + d0 + dl) * HH + (j * 8 + hl) * 4];
            Vl[j] = (f32x2){vv.x, vv.y};  Vh[j] = (f32x2){vv.z, vv.w};
            Bl[j] = (f32x2){bb.x, bb.y};  Bh[j] = (f32x2){bb.z, bb.w};
            Pl[j] = Vl[j] * Bl[j];        Ph[j] = Vh[j] * Bh[j];
        }

        const float* ta_b = ta + (size_t)b * TE * HH;

        // Wave w covers rows {(i>>1)*64 + w*8 + (i&1)*4 + rp}, i = 0..31:
        // same ascending octet sweep as the proven DTILE=4 version.
        auto rowOf = [&](int i) {
            return ((i >> 1) << 6) + w * 8 + ((i & 1) << 2) + rp;
        };

        float4 A0[4], A1[4];
        auto loadA = [&](int i, float4 (&A)[4]) {
            const float* base = ta_b + (size_t)rowOf(i) * HH;
            #pragma unroll
            for (int j = 0; j < 4; ++j)
                A[j] = *(const float4*)&base[(j * 8 + hl) * 4];
        };

        auto p1c = [&](int i, float4 (&A)[4]) {
            const f32x2 one2 = {1.0f, 1.0f};
            f32x2 n2[8], d2[8];
            #pragma unroll
            for (int j = 0; j < 4; ++j) {
                f32x2 Al = (f32x2){A[j].x, A[j].y};
                f32x2 Ah = (f32x2){A[j].z, A[j].w};
                n2[2 * j]     = pk_fma(Vl[j], Al, Pl[j]);
                n2[2 * j + 1] = pk_fma(Vh[j], Ah, Ph[j]);
                d2[2 * j]     = pk_fma(Al, Bl[j], one2);
                d2[2 * j + 1] = pk_fma(Ah, Bh[j], one2);
            }
            // Vertical packed fraction-combine tree: 8 -> 4 -> 2 -> 1.
            #pragma unroll
            for (int s = 4; s >= 1; s >>= 1) {
                #pragma unroll
                for (int k = 0; k < s; ++k) {
                    n2[k] = pk_fma(n2[2 * k], d2[2 * k + 1], n2[2 * k + 1] * d2[2 * k]);
                    d2[k] = d2[2 * k] * d2[2 * k + 1];
                }
            }
            // Horizontal: combine the two sub-fractions in .x/.y.
            float num = n2[0].x * d2[0].y + n2[0].y * d2[0].x;
            float den = d2[0].x * d2[0].y;
            float e = num * __builtin_amdgcn_rcpf(den);
            e += __shfl_xor(e, 1);
            e += __shfl_xor(e, 2);
            e += __shfl_xor(e, 4);
            if (hl == 0) e_s[dl * ESTR + rowOf(i)] = e;
        };

        loadA(0, A0);
        #pragma unroll 1
        for (int i = 0; i < 30; i += 2) {
            loadA(i + 1, A1);
            p1c(i, A0);
            loadA(i + 2, A0);
            p1c(i + 1, A1);
        }
        loadA(31, A1);
        p1c(30, A0);
        p1c(31, A1);
    }
    __syncthreads();   // all waves' raw energies visible

    // ------------- Phase 2: softmax (d = w&1, four waves split quarters) ----
    {
        const int d2 = w & 1, q = w >> 1;   // q = 0..3
        float ev[16];
        float m = -3.0e38f;
        #pragma unroll
        for (int i = 0; i < 16; ++i) {
            ev[i] = e_s[d2 * ESTR + i * 64 + l];
            m = fmaxf(m, ev[i]);
        }
        #pragma unroll
        for (int off = 32; off; off >>= 1) m = fmaxf(m, __shfl_xor(m, off));
        float s = 0.f;
        #pragma unroll
        for (int i = 0; i < 16; ++i) {
            ev[i] = __builtin_amdgcn_exp2f((ev[i] - m) * LOG2E);
            s += ev[i];
        }
        #pragma unroll
        for (int off = 32; off; off >>= 1) s += __shfl_xor(s, off);
        float inv = __builtin_amdgcn_rcpf(s);

        __syncthreads();   // all raw-energy reads done before overwrite
        float* eo = e_out + ((size_t)b * TD + d0 + d2) * TE;
        #pragma unroll
        for (int i = 0; i < 4; ++i) {
            int ii = q * 4 + i;
            float p = ev[ii] * inv;
            e_s[d2 * ESTR + ii * 64 + l] = p;
            eo[ii * 64 + l] = p;
        }
        __syncthreads();   // normalized p visible to all waves
    }

    // ---------------- Phase 3: context (packed FMAs, register pingpong) -----
    const int h4 = l & 31, tsub = l >> 5;
    f32x2 accL[DTILE], accH[DTILE];
    #pragma unroll
    for (int d = 0; d < DTILE; ++d) {
        accL[d] = (f32x2){0.f, 0.f};
        accH[d] = (f32x2){0.f, 0.f};
    }

    {
        const float* enc_w = enc + ((size_t)b * TE + w * 8) * HH;
        float4 X0[4], X1[4];

        auto loadX = [&](int tt, float4 (&X)[4]) {
            const float* base = enc_w + (size_t)tt * TTILE * HH;
            #pragma unroll
            for (int k = 0; k < 4; ++k)
                X[k] = *(const float4*)&base[(tsub * 4 + k) * HH + h4 * 4];
        };

        auto p3c = [&](int tt, float4 (&X)[4]) {
            float4 ep[DTILE];
            #pragma unroll
            for (int d = 0; d < DTILE; ++d)
                ep[d] = *(const float4*)&e_s[d * ESTR + tt * TTILE + w * 8 + tsub * 4];
            #pragma unroll
            for (int k = 0; k < 4; ++k) {
                f32x2 xL = (f32x2){X[k].x, X[k].y};
                f32x2 xH = (f32x2){X[k].z, X[k].w};
                #pragma unroll
                for (int d = 0; d < DTILE; ++d) {
                    float p = k == 0 ? ep[d].x : k == 1 ? ep[d].y
                            : k == 2 ? ep[d].z : ep[d].w;
                    f32x2 pv = (f32x2){p, p};
                    accL[d] = pk_fma(pv, xL, accL[d]);
                    accH[d] = pk_fma(pv, xH, accH[d]);
                }
            }
        };

        loadX(0, X0);
        #pragma unroll 1
        for (int tt = 0; tt < 14; tt += 2) {
            loadX(tt + 1, X1);
            p3c(tt, X0);
            loadX(tt + 2, X0);
            p3c(tt + 1, X1);
        }
        loadX(15, X1);
        p3c(14, X0);
        p3c(15, X1);
    }

    // Combine tsub halves; park per-wave partials; tree-reduce across waves.
    float4 acc4[DTILE];
    #pragma unroll
    for (int d = 0; d < DTILE; ++d)
        acc4[d] = make_float4(accL[d].x, accL[d].y, accH[d].x, accH[d].y);
    #pragma unroll
    for (int d = 0; d < DTILE; ++d) {
        acc4[d].x += __shfl_xor(acc4[d].x, 32);
        acc4[d].y += __shfl_xor(acc4[d].y, 32);
        acc4[d].z += __shfl_xor(acc4[d].z, 32);
        acc4[d].w += __shfl_xor(acc4[d].w, 32);
    }
    if (tsub == 0) {
        #pragma unroll
        for (int d = 0; d < DTILE; ++d)
            *(float4*)&c_red[(w * DTILE + d) * HH + h4 * 4] = acc4[d];
    }
    __syncthreads();

    if (w < DTILE && l < 32) {
        float4 o = make_float4(0.f, 0.f, 0.f, 0.f);
        #pragma unroll
        for (int ww = 0; ww < 8; ++ww) {
            float4 p = *(const float4*)&c_red[(ww * DTILE + w) * HH + l * 4];
            o.x += p.x; o.y += p.y; o.z += p.z; o.w += p.w;
        }
        *(float4*)&c_out[((size_t)b * TD + d0 + w) * HH + l * 4] = o;
    }
}

// ---------------------------------------------------------------------------
extern "C" void kernel_launch(void* const* d_in, const int* in_sizes, int n_in,
                              void* d_out, int out_size, void* d_ws, size_t ws_size,
                              hipStream_t stream) {
    (void)in_sizes; (void)n_in; (void)out_size; (void)ws_size;

    const float* enc = (const float*)d_in[0];
    const float* dec = (const float*)d_in[1];
    const float* Wa  = (const float*)d_in[2];
    const float* Ua  = (const float*)d_in[3];
    const float* Va  = (const float*)d_in[4];

    float* c_out = (float*)d_out;
    float* e_out = (float*)d_out + BB * TD * HH;

    float* proj = (float*)d_ws;
    float* ta_p = proj;                  // tanh(W_s): [B*TE, H]
    float* tb_p = proj + BB * TE * HH;   // tanh(U_h): [B*TD, H]

    proj_gemm<<<384, 512, 0, stream>>>(enc, dec, Wa, Ua, proj);
    attn_fused<<<(BB * TD) / DTILE, 512, 0, stream>>>(enc, ta_p, tb_p, Va, c_out, e_out);
}

// Round 7
// 121.424 us; speedup vs baseline: 2.8359x; 1.0503x over previous
//
#include <hip/hip_runtime.h>

#define BB    4
#define TE    1024
#define TD    512
#define HH    128
#define DTILE 4
#define TTILE 64
#define ESTR  (TE + 8)              // e_s row stride: breaks d-bank aliasing
#define LOG2E 1.4426950408889634f

typedef float f32x2 __attribute__((ext_vector_type(2)));

__device__ __forceinline__ f32x2 pk_fma(f32x2 a, f32x2 b, f32x2 c) {
    return __builtin_elementwise_fma(a, b, c);
}

// Accurate-enough tanh for the proj epilogue (786K elems, off the hot path).
__device__ __forceinline__ float tanh_eval(float x) {
    float e = __builtin_amdgcn_exp2f(2.0f * LOG2E * x);
    return 1.0f - 2.0f * __builtin_amdgcn_rcpf(e + 1.0f);
}

// ---------------------------------------------------------------------------
// Kernel 1: skinny projections (M=6144, N=128, K=128) with tanh epilogue.
// R14 LDS-staged-W version, EXACTLY as in the 120.76us round-4 bench.
// ---------------------------------------------------------------------------
__global__ __launch_bounds__(512, 2) void proj_gemm(
    const float* __restrict__ enc, const float* __restrict__ dec,
    const float* __restrict__ Wa,  const float* __restrict__ Ua,
    float* __restrict__ out)
{
    __shared__ float Ws[HH * HH];   // 64 KB: W[k][c], row-major
    __shared__ float Xs[16 * HH];   // 8 KB

    const int tid = threadIdx.x;
    const int r0  = blockIdx.x * 16;

    const float* X; const float* W; int rX0;
    if (r0 < BB * TE) { X = enc; W = Wa; rX0 = r0; }
    else              { X = dec; W = Ua; rX0 = r0 - BB * TE; }

    #pragma unroll
    for (int i = 0; i < 8; ++i)
        *(float4*)&Ws[i * 2048 + tid * 4] =
            *(const float4*)&W[i * 2048 + tid * 4];

    {
        const int r = tid >> 5, c = tid & 31;
        *(float4*)&Xs[r * HH + c * 4] =
            *(const float4*)&X[(size_t)(rX0 + r) * HH + c * 4];
    }
    __syncthreads();

    const int rr = tid >> 5;        // 0..15 : output row within tile
    const int c4 = tid & 31;        // 0..31 : output float4 column group

    f32x2 aL0 = {0.f, 0.f}, aH0 = {0.f, 0.f};
    f32x2 aL1 = {0.f, 0.f}, aH1 = {0.f, 0.f};

    const float* wc   = &Ws[c4 * 4];
    const float* xrow = &Xs[rr * HH];

    #pragma unroll 4
    for (int k = 0; k < HH; k += 4) {
        float4 w0 = *(const float4*)&wc[(k + 0) * HH];
        float4 w1 = *(const float4*)&wc[(k + 1) * HH];
        float4 w2 = *(const float4*)&wc[(k + 2) * HH];
        float4 w3 = *(const float4*)&wc[(k + 3) * HH];
        float4 xv = *(const float4*)&xrow[k];

        aL0 = pk_fma((f32x2){xv.x, xv.x}, (f32x2){w0.x, w0.y}, aL0);
        aH0 = pk_fma((f32x2){xv.x, xv.x}, (f32x2){w0.z, w0.w}, aH0);
        aL1 = pk_fma((f32x2){xv.y, xv.y}, (f32x2){w1.x, w1.y}, aL1);
        aH1 = pk_fma((f32x2){xv.y, xv.y}, (f32x2){w1.z, w1.w}, aH1);
        aL0 = pk_fma((f32x2){xv.z, xv.z}, (f32x2){w2.x, w2.y}, aL0);
        aH0 = pk_fma((f32x2){xv.z, xv.z}, (f32x2){w2.z, w2.w}, aH0);
        aL1 = pk_fma((f32x2){xv.w, xv.w}, (f32x2){w3.x, w3.y}, aL1);
        aH1 = pk_fma((f32x2){xv.w, xv.w}, (f32x2){w3.z, w3.w}, aH1);
    }

    f32x2 aL = aL0 + aL1;
    f32x2 aH = aH0 + aH1;

    float4 o;
    o.x = tanh_eval(aL.x); o.y = tanh_eval(aL.y);
    o.z = tanh_eval(aH.x); o.w = tanh_eval(aH.y);
    *(float4*)&out[(size_t)(r0 + rr) * HH + c4 * 4] = o;
}

// ---------------------------------------------------------------------------
// Kernel 2: fused energies -> softmax -> context.
//
// R17: revert to the PROVEN round-4 choreography (57.4us; R15 died of
// launch_bounds-forced VGPR=32 spill, R16's DTILE=2 doubled softmax
// redundancy for no occupancy gain). Two serialization cuts, zero change
// to the load/store pattern:
//  (a) normalized p goes to a SEPARATE p_s buffer -> the mid-phase-2
//      barrier (which only guarded the e_s overwrite) is removed: 3 -> 2
//      barriers per block.
//  (b) phase-3's first X tile is prefetched at kernel start (depends only
//      on enc) -> first-use latency fully hidden. +16 VGPR, cap 128.
// ---------------------------------------------------------------------------
__global__ __launch_bounds__(512, 4) void attn_fused(
    const float* __restrict__ enc,    // [B, TE, H] raw
    const float* __restrict__ ta,     // [B*TE, H]  = tanh(W_s)
    const float* __restrict__ tb,     // [B*TD, H]  = tanh(U_h)
    const float* __restrict__ Va,     // [H]
    float* __restrict__ c_out,        // [B, TD, H]
    float* __restrict__ e_out)        // [B, TD, TE]
{
    __shared__ float e_s[DTILE * ESTR];     // 16.5 KB raw energies
    __shared__ float p_s[DTILE * TE];       // 16 KB   normalized p
    __shared__ float c_red[8 * DTILE * HH]; // 16 KB

    const int tid = threadIdx.x;
    const int l   = tid & 63;
    const int w   = tid >> 6;            // 0..7 (row-octet owner)
    const int b   = blockIdx.x >> 7;
    const int d0  = (blockIdx.x & 127) * DTILE;

    // Phase-3 lane mapping + tile-0 prefetch (independent of e_s/p_s).
    const int h4 = l & 31, tsub = l >> 5;
    const float* enc_w = enc + ((size_t)b * TE + w * 8) * HH;
    float4 X0[4], X1[4];
    #pragma unroll
    for (int k = 0; k < 4; ++k)
        X0[k] = *(const float4*)&enc_w[(size_t)(tsub * 4 + k) * HH + h4 * 4];

    // ---------------- Phase 1: energies ----------------
    {
        const int g  = l >> 3;           // group 0..7
        const int hl = l & 7;            // h-chunk offset within group
        const int dl = g & 3;            // this group's decoder step
        const int rh = g >> 2;           // row parity

        // Lane constants as f32x2: B, Bp = v*B, v (24 f32x2 = 48 regs).
        f32x2 Bl[4], Bh[4], Pl[4], Ph[4], Vl[4], Vh[4];
        #pragma unroll
        for (int j = 0; j < 4; ++j) {
            float4 vv = *(const float4*)&Va[(j * 8 + hl) * 4];
            float4 bb = *(const float4*)&tb[((size_t)b * TD + d0 + dl) * HH + (j * 8 + hl) * 4];
            Vl[j] = (f32x2){vv.x, vv.y};  Vh[j] = (f32x2){vv.z, vv.w};
            Bl[j] = (f32x2){bb.x, bb.y};  Bh[j] = (f32x2){bb.z, bb.w};
            Pl[j] = Vl[j] * Bl[j];        Ph[j] = Vh[j] * Bh[j];
        }

        const float* ta_b = ta + (size_t)b * TE * HH;

        // Wave w covers rows {(i>>2)*64 + w*8 + (i&3)*2 + rh}, i = 0..63.
        auto rowOf = [&](int i) {
            return ((i >> 2) << 6) + w * 8 + ((i & 3) << 1) + rh;
        };

        float4 A0[4], A1[4];
        auto loadA = [&](int i, float4 (&A)[4]) {
            const float* base = ta_b + (size_t)rowOf(i) * HH;
            #pragma unroll
            for (int j = 0; j < 4; ++j)
                A[j] = *(const float4*)&base[(j * 8 + hl) * 4];
        };

        auto p1c = [&](int i, float4 (&A)[4]) {
            const f32x2 one2 = {1.0f, 1.0f};
            f32x2 n2[8], d2[8];
            #pragma unroll
            for (int j = 0; j < 4; ++j) {
                f32x2 Al = (f32x2){A[j].x, A[j].y};
                f32x2 Ah = (f32x2){A[j].z, A[j].w};
                n2[2 * j]     = pk_fma(Vl[j], Al, Pl[j]);
                n2[2 * j + 1] = pk_fma(Vh[j], Ah, Ph[j]);
                d2[2 * j]     = pk_fma(Al, Bl[j], one2);
                d2[2 * j + 1] = pk_fma(Ah, Bh[j], one2);
            }
            // Vertical packed fraction-combine tree: 8 -> 4 -> 2 -> 1.
            #pragma unroll
            for (int s = 4; s >= 1; s >>= 1) {
                #pragma unroll
                for (int k = 0; k < s; ++k) {
                    n2[k] = pk_fma(n2[2 * k], d2[2 * k + 1], n2[2 * k + 1] * d2[2 * k]);
                    d2[k] = d2[2 * k] * d2[2 * k + 1];
                }
            }
            // Horizontal: combine the two sub-fractions in .x/.y.
            float num = n2[0].x * d2[0].y + n2[0].y * d2[0].x;
            float den = d2[0].x * d2[0].y;
            float e = num * __builtin_amdgcn_rcpf(den);
            e += __shfl_xor(e, 1);
            e += __shfl_xor(e, 2);
            e += __shfl_xor(e, 4);
            if (hl == 0) e_s[dl * ESTR + rowOf(i)] = e;
        };

        loadA(0, A0);
        #pragma unroll 1
        for (int i = 0; i < 62; i += 2) {
            loadA(i + 1, A1);
            p1c(i, A0);
            loadA(i + 2, A0);
            p1c(i + 1, A1);
        }
        loadA(63, A1);
        p1c(62, A0);
        p1c(63, A1);
    }
    __syncthreads();   // all waves' raw energies visible

    // ------- Phase 2: softmax (d = w&3, two waves split halves; no mid-barrier)
    {
        const int d2 = w & 3, hf = w >> 2;
        float ev[16];
        float m = -3.0e38f;
        #pragma unroll
        for (int i = 0; i < 16; ++i) {
            ev[i] = e_s[d2 * ESTR + i * 64 + l];
            m = fmaxf(m, ev[i]);
        }
        #pragma unroll
        for (int off = 32; off; off >>= 1) m = fmaxf(m, __shfl_xor(m, off));
        float s = 0.f;
        #pragma unroll
        for (int i = 0; i < 16; ++i) {
            ev[i] = __builtin_amdgcn_exp2f((ev[i] - m) * LOG2E);
            s += ev[i];
        }
        #pragma unroll
        for (int off = 32; off; off >>= 1) s += __shfl_xor(s, off);
        float inv = __builtin_amdgcn_rcpf(s);

        // Writes go to p_s (not e_s) -> no barrier needed before them.
        float* eo = e_out + ((size_t)b * TD + d0 + d2) * TE;
        #pragma unroll
        for (int i = 0; i < 8; ++i) {
            int ii = hf * 8 + i;
            float p = ev[ii] * inv;
            p_s[d2 * TE + ii * 64 + l] = p;
            eo[ii * 64 + l] = p;
        }
        __syncthreads();   // normalized p visible to all waves
    }

    // ---------------- Phase 3: context (packed FMAs, register pingpong) -----
    f32x2 accL[DTILE], accH[DTILE];
    #pragma unroll
    for (int d = 0; d < DTILE; ++d) {
        accL[d] = (f32x2){0.f, 0.f};
        accH[d] = (f32x2){0.f, 0.f};
    }

    {
        auto loadX = [&](int tt, float4 (&X)[4]) {
            const float* base = enc_w + (size_t)tt * TTILE * HH;
            #pragma unroll
            for (int k = 0; k < 4; ++k)
                X[k] = *(const float4*)&base[(tsub * 4 + k) * HH + h4 * 4];
        };

        auto p3c = [&](int tt, float4 (&X)[4]) {
            float4 ep[DTILE];
            #pragma unroll
            for (int d = 0; d < DTILE; ++d)
                ep[d] = *(const float4*)&p_s[d * TE + tt * TTILE + w * 8 + tsub * 4];
            #pragma unroll
            for (int k = 0; k < 4; ++k) {
                f32x2 xL = (f32x2){X[k].x, X[k].y};
                f32x2 xH = (f32x2){X[k].z, X[k].w};
                #pragma unroll
                for (int d = 0; d < DTILE; ++d) {
                    float p = k == 0 ? ep[d].x : k == 1 ? ep[d].y
                            : k == 2 ? ep[d].z : ep[d].w;
                    f32x2 pv = (f32x2){p, p};
                    accL[d] = pk_fma(pv, xL, accL[d]);
                    accH[d] = pk_fma(pv, xH, accH[d]);
                }
            }
        };

        // X0 (tile 0) was prefetched at kernel start.
        #pragma unroll 1
        for (int tt = 0; tt < 14; tt += 2) {
            loadX(tt + 1, X1);
            p3c(tt, X0);
            loadX(tt + 2, X0);
            p3c(tt + 1, X1);
        }
        loadX(15, X1);
        p3c(14, X0);
        p3c(15, X1);
    }

    // Combine tsub halves; park per-wave partials; tree-reduce across waves.
    float4 acc4[DTILE];
    #pragma unroll
    for (int d = 0; d < DTILE; ++d)
        acc4[d] = make_float4(accL[d].x, accL[d].y, accH[d].x, accH[d].y);
    #pragma unroll
    for (int d = 0; d < DTILE; ++d) {
        acc4[d].x += __shfl_xor(acc4[d].x, 32);
        acc4[d].y += __shfl_xor(acc4[d].y, 32);
        acc4[d].z += __shfl_xor(acc4[d].z, 32);
        acc4[d].w += __shfl_xor(acc4[d].w, 32);
    }
    if (tsub == 0) {
        #pragma unroll
        for (int d = 0; d < DTILE; ++d)
            *(float4*)&c_red[(w * DTILE + d) * HH + h4 * 4] = acc4[d];
    }
    __syncthreads();

    if (w < DTILE && l < 32) {
        float4 o = make_float4(0.f, 0.f, 0.f, 0.f);
        #pragma unroll
        for (int ww = 0; ww < 8; ++ww) {
            float4 p = *(const float4*)&c_red[(ww * DTILE + w) * HH + l * 4];
            o.x += p.x; o.y += p.y; o.z += p.z; o.w += p.w;
        }
        *(float4*)&c_out[((size_t)b * TD + d0 + w) * HH + l * 4] = o;
    }
}

// ---------------------------------------------------------------------------
extern "C" void kernel_launch(void* const* d_in, const int* in_sizes, int n_in,
                              void* d_out, int out_size, void* d_ws, size_t ws_size,
                              hipStream_t stream) {
    (void)in_sizes; (void)n_in; (void)out_size; (void)ws_size;

    const float* enc = (const float*)d_in[0];
    const float* dec = (const float*)d_in[1];
    const float* Wa  = (const float*)d_in[2];
    const float* Ua  = (const float*)d_in[3];
    const float* Va  = (const float*)d_in[4];

    float* c_out = (float*)d_out;
    float* e_out = (float*)d_out + BB * TD * HH;

    float* proj = (float*)d_ws;
    float* ta_p = proj;                  // tanh(W_s): [B*TE, H]
    float* tb_p = proj + BB * TE * HH;   // tanh(U_h): [B*TD, H]

    proj_gemm<<<384, 512, 0, stream>>>(enc, dec, Wa, Ua, proj);
    attn_fused<<<(BB * TD) / DTILE, 512, 0, stream>>>(enc, ta_p, tb_p, Va, c_out, e_out);
}